// Round 1
// baseline (2262.028 us; speedup 1.0000x reference)
//
#include <hip/hip_runtime.h>
#include <hip/hip_bf16.h>

#define T_SEQ 512
#define BATCH 16
#define EMB 768
#define HEADS 32
#define HDIM 24
#define ROWS (T_SEQ * BATCH)  /* 8192 */
#define SCALING 0.20412414523193154f /* 24^-0.5 */

// ---------------------------------------------------------------------------
// Fused QKV projection: X[8192,768] @ W^T + b for W in {Wq,Wk,Wv}.
// Output layout [bh = b*32+h][t][dd] so attention reads are contiguous.
// Tile: 128x128, BK=16, 256 threads, 8x8 micro-tile (2x2 blocks of 4x4).
// LDS stored k-outer so ALL inner-loop reads are ds_read_b128.
// Stride 132 floats: 16B-aligned rows, max 2-way bank alias (free).
// ---------------------------------------------------------------------------
__global__ __launch_bounds__(256)
void qkv_proj_kernel(const float* __restrict__ X,
                     const float* __restrict__ Wq, const float* __restrict__ Wk,
                     const float* __restrict__ Wv,
                     const float* __restrict__ bq, const float* __restrict__ bk,
                     const float* __restrict__ bv,
                     float* __restrict__ qo, float* __restrict__ ko,
                     float* __restrict__ vo)
{
    __shared__ __attribute__((aligned(16))) float Xs[16][132];
    __shared__ __attribute__((aligned(16))) float Ws[16][132];

    const int tid = threadIdx.x;
    const int r0 = blockIdx.x * 128;
    const int nb = blockIdx.y;            // 0..17 -> (q|k|v) x 6 col-blocks
    const int which = nb / 6;
    const int n0 = (nb % 6) * 128;
    const float* W    = (which == 0) ? Wq : (which == 1) ? Wk : Wv;
    const float* bias = (which == 0) ? bq : (which == 1) ? bk : bv;
    float* out        = (which == 0) ? qo : (which == 1) ? ko : vo;

    const int tx = tid & 15;              // n-dir
    const int ty = tid >> 4;              // m-dir

    const int srow = tid >> 2;            // 0..63
    const int skq  = (tid & 3) << 2;      // 0,4,8,12

    float acc[8][8] = {};

    for (int k0 = 0; k0 < EMB; k0 += 16) {
        const float4 x0 = *(const float4*)(X + (size_t)(r0 + srow) * EMB + k0 + skq);
        const float4 x1 = *(const float4*)(X + (size_t)(r0 + srow + 64) * EMB + k0 + skq);
        const float4 w0 = *(const float4*)(W + (size_t)(n0 + srow) * EMB + k0 + skq);
        const float4 w1 = *(const float4*)(W + (size_t)(n0 + srow + 64) * EMB + k0 + skq);
        __syncthreads();                  // previous iteration's reads complete
        Xs[skq + 0][srow] = x0.x; Xs[skq + 1][srow] = x0.y;
        Xs[skq + 2][srow] = x0.z; Xs[skq + 3][srow] = x0.w;
        Xs[skq + 0][srow + 64] = x1.x; Xs[skq + 1][srow + 64] = x1.y;
        Xs[skq + 2][srow + 64] = x1.z; Xs[skq + 3][srow + 64] = x1.w;
        Ws[skq + 0][srow] = w0.x; Ws[skq + 1][srow] = w0.y;
        Ws[skq + 2][srow] = w0.z; Ws[skq + 3][srow] = w0.w;
        Ws[skq + 0][srow + 64] = w1.x; Ws[skq + 1][srow + 64] = w1.y;
        Ws[skq + 2][srow + 64] = w1.z; Ws[skq + 3][srow + 64] = w1.w;
        __syncthreads();
#pragma unroll
        for (int kk = 0; kk < 16; ++kk) {
            const float4 a0 = *(const float4*)&Xs[kk][ty * 4];
            const float4 a1 = *(const float4*)&Xs[kk][ty * 4 + 64];
            const float4 b0 = *(const float4*)&Ws[kk][tx * 4];
            const float4 b1 = *(const float4*)&Ws[kk][tx * 4 + 64];
            const float a[8] = {a0.x, a0.y, a0.z, a0.w, a1.x, a1.y, a1.z, a1.w};
            const float b[8] = {b0.x, b0.y, b0.z, b0.w, b1.x, b1.y, b1.z, b1.w};
#pragma unroll
            for (int ii = 0; ii < 8; ++ii)
#pragma unroll
                for (int jj = 0; jj < 8; ++jj)
                    acc[ii][jj] += a[ii] * b[jj];
        }
    }

#pragma unroll
    for (int im = 0; im < 2; ++im)
#pragma unroll
    for (int ii = 0; ii < 4; ++ii) {
        const int rr = r0 + im * 64 + ty * 4 + ii;
        const int t = rr >> 4;
        const int b = rr & 15;
#pragma unroll
        for (int jn = 0; jn < 2; ++jn)
#pragma unroll
        for (int jj = 0; jj < 4; ++jj) {
            const int nn = n0 + jn * 64 + tx * 4 + jj;
            float c = acc[im * 4 + ii][jn * 4 + jj] + bias[nn];
            if (which == 0) c *= SCALING;
            const int h = nn / HDIM;
            const int dd = nn - h * HDIM;
            out[((size_t)((b * HEADS + h) * T_SEQ + t)) * HDIM + dd] = c;
        }
    }
}

// ---------------------------------------------------------------------------
// Attention: one block per (bh, 16 query rows). Scores (16x512) in LDS,
// two-pass softmax, then PV. Bias streamed coalesced (the 512 MB read).
// Score loop: Q held in registers (thread owns one row), K rows load as
// dwordx4 from L1/L2 — no LDS reads on the QK^T critical path.
// ---------------------------------------------------------------------------
__global__ __launch_bounds__(256)
void attn_kernel(const float* __restrict__ qb, const float* __restrict__ kb,
                 const float* __restrict__ vb, const float* __restrict__ bias,
                 float* __restrict__ attn)
{
    const int bh = blockIdx.x;            // 0..511  (= b*32 + h)
    const int t0 = blockIdx.y * 16;
    const int tid = threadIdx.x;

    __shared__ float Ss[16][513];         // 513: i-dependent bank rotation
    __shared__ float red[16][17];
    __shared__ float rowm[16];
    __shared__ float rowl[16];

    const float* Kb = kb + (size_t)bh * T_SEQ * HDIM;
    const float* Vb = vb + (size_t)bh * T_SEQ * HDIM;
    const float* Bb = bias + (size_t)bh * T_SEQ * T_SEQ + (size_t)t0 * T_SEQ;

    const int i = tid >> 4;               // query row 0..15
    const int g = tid & 15;               // lane group within row

    // Q row into registers (16 threads per row read the same 96 B row; L1 hit)
    float q[HDIM];
    {
        const float* qr = qb + ((size_t)bh * T_SEQ + t0 + i) * HDIM;
#pragma unroll
        for (int dd = 0; dd < HDIM; ++dd) q[dd] = qr[dd];
    }

    // scores = (scaled q) . k + bias
    for (int s = g; s < T_SEQ; s += 16) {
        const float* kr = Kb + s * HDIM;
        float d = 0.f;
#pragma unroll
        for (int dd = 0; dd < HDIM; ++dd) d += q[dd] * kr[dd];
        Ss[i][s] = d + Bb[i * T_SEQ + s];
    }
    __syncthreads();

    // softmax per row (16 threads per row)
    float m = -1e30f;
    for (int s = g; s < T_SEQ; s += 16) m = fmaxf(m, Ss[i][s]);
    red[i][g] = m;
    __syncthreads();
    if (g == 0) {
        float mm = red[i][0];
#pragma unroll
        for (int j = 1; j < 16; ++j) mm = fmaxf(mm, red[i][j]);
        rowm[i] = mm;
    }
    __syncthreads();
    const float mrow = rowm[i];
    float l = 0.f;
    for (int s = g; s < T_SEQ; s += 16) {
        const float p = __expf(Ss[i][s] - mrow);
        Ss[i][s] = p;
        l += p;
    }
    red[i][g] = l;
    __syncthreads();
    if (g == 0) {
        float ll = 0.f;
#pragma unroll
        for (int j = 0; j < 16; ++j) ll += red[i][j];
        rowl[i] = 1.f / ll;
    }
    __syncthreads();

    // PV: out[i][dd] = (1/l) * sum_s P[i][s] * V[s][dd]
    for (int p = tid; p < 16 * HDIM; p += 256) {
        const int ii = p / HDIM, dd = p - ii * HDIM;
        float accv = 0.f;
        const float* vp = Vb + dd;
#pragma unroll 8
        for (int s = 0; s < T_SEQ; ++s) accv += Ss[ii][s] * vp[s * HDIM];
        accv *= rowl[ii];
        const int t = t0 + ii;
        const int b = bh >> 5;
        const int h = bh & 31;
        attn[((size_t)(t * BATCH + b)) * EMB + h * HDIM + dd] = accv;
    }
}

// ---------------------------------------------------------------------------
// Output projection: attn[8192,768] @ Wo^T + bo -> out (same 128x128 tile)
// ---------------------------------------------------------------------------
__global__ __launch_bounds__(256)
void out_proj_kernel(const float* __restrict__ A, const float* __restrict__ Wo,
                     const float* __restrict__ bo, float* __restrict__ out)
{
    __shared__ __attribute__((aligned(16))) float Xs[16][132];
    __shared__ __attribute__((aligned(16))) float Ws[16][132];

    const int tid = threadIdx.x;
    const int r0 = blockIdx.x * 128;
    const int n0 = blockIdx.y * 128;

    const int tx = tid & 15;
    const int ty = tid >> 4;

    const int srow = tid >> 2;
    const int skq  = (tid & 3) << 2;

    float acc[8][8] = {};

    for (int k0 = 0; k0 < EMB; k0 += 16) {
        const float4 x0 = *(const float4*)(A + (size_t)(r0 + srow) * EMB + k0 + skq);
        const float4 x1 = *(const float4*)(A + (size_t)(r0 + srow + 64) * EMB + k0 + skq);
        const float4 w0 = *(const float4*)(Wo + (size_t)(n0 + srow) * EMB + k0 + skq);
        const float4 w1 = *(const float4*)(Wo + (size_t)(n0 + srow + 64) * EMB + k0 + skq);
        __syncthreads();
        Xs[skq + 0][srow] = x0.x; Xs[skq + 1][srow] = x0.y;
        Xs[skq + 2][srow] = x0.z; Xs[skq + 3][srow] = x0.w;
        Xs[skq + 0][srow + 64] = x1.x; Xs[skq + 1][srow + 64] = x1.y;
        Xs[skq + 2][srow + 64] = x1.z; Xs[skq + 3][srow + 64] = x1.w;
        Ws[skq + 0][srow] = w0.x; Ws[skq + 1][srow] = w0.y;
        Ws[skq + 2][srow] = w0.z; Ws[skq + 3][srow] = w0.w;
        Ws[skq + 0][srow + 64] = w1.x; Ws[skq + 1][srow + 64] = w1.y;
        Ws[skq + 2][srow + 64] = w1.z; Ws[skq + 3][srow + 64] = w1.w;
        __syncthreads();
#pragma unroll
        for (int kk = 0; kk < 16; ++kk) {
            const float4 a0 = *(const float4*)&Xs[kk][ty * 4];
            const float4 a1 = *(const float4*)&Xs[kk][ty * 4 + 64];
            const float4 b0 = *(const float4*)&Ws[kk][tx * 4];
            const float4 b1 = *(const float4*)&Ws[kk][tx * 4 + 64];
            const float a[8] = {a0.x, a0.y, a0.z, a0.w, a1.x, a1.y, a1.z, a1.w};
            const float b[8] = {b0.x, b0.y, b0.z, b0.w, b1.x, b1.y, b1.z, b1.w};
#pragma unroll
            for (int ii = 0; ii < 8; ++ii)
#pragma unroll
                for (int jj = 0; jj < 8; ++jj)
                    acc[ii][jj] += a[ii] * b[jj];
        }
    }

    const float4 bo0 = *(const float4*)(bo + n0 + tx * 4);
    const float4 bo1 = *(const float4*)(bo + n0 + 64 + tx * 4);
#pragma unroll
    for (int im = 0; im < 2; ++im)
#pragma unroll
    for (int ii = 0; ii < 4; ++ii) {
        const int rr = r0 + im * 64 + ty * 4 + ii;
        float4 c0, c1;
        c0.x = acc[im * 4 + ii][0] + bo0.x; c0.y = acc[im * 4 + ii][1] + bo0.y;
        c0.z = acc[im * 4 + ii][2] + bo0.z; c0.w = acc[im * 4 + ii][3] + bo0.w;
        c1.x = acc[im * 4 + ii][4] + bo1.x; c1.y = acc[im * 4 + ii][5] + bo1.y;
        c1.z = acc[im * 4 + ii][6] + bo1.z; c1.w = acc[im * 4 + ii][7] + bo1.w;
        *(float4*)(out + (size_t)rr * EMB + n0 + tx * 4) = c0;
        *(float4*)(out + (size_t)rr * EMB + n0 + 64 + tx * 4) = c1;
    }
}

extern "C" void kernel_launch(void* const* d_in, const int* in_sizes, int n_in,
                              void* d_out, int out_size, void* d_ws, size_t ws_size,
                              hipStream_t stream)
{
    const float* query = (const float*)d_in[0];   // [512,16,768]
    const float* abias = (const float*)d_in[1];   // [512,512,512]
    const float* Wq = (const float*)d_in[2];
    const float* bq = (const float*)d_in[3];
    const float* Wk = (const float*)d_in[4];
    const float* bk = (const float*)d_in[5];
    const float* Wv = (const float*)d_in[6];
    const float* bv = (const float*)d_in[7];
    const float* Wo = (const float*)d_in[8];
    const float* bo = (const float*)d_in[9];
    float* out = (float*)d_out;

    // workspace layout (floats): q | k | v | attn, each 512*512*24 or 8192*768
    float* ws = (float*)d_ws;
    const size_t QKV_ELEMS = (size_t)BATCH * HEADS * T_SEQ * HDIM; // 6291456
    float* qb = ws;
    float* kb = ws + QKV_ELEMS;
    float* vb = ws + 2 * QKV_ELEMS;
    float* ab = ws + 3 * QKV_ELEMS;                                // [8192,768]

    dim3 gA(ROWS / 128, 18);
    qkv_proj_kernel<<<gA, 256, 0, stream>>>(query, Wq, Wk, Wv, bq, bk, bv, qb, kb, vb);

    dim3 gB(BATCH * HEADS, T_SEQ / 16);
    attn_kernel<<<gB, 256, 0, stream>>>(qb, kb, vb, abias, ab);

    dim3 gC(ROWS / 128, EMB / 128);
    out_proj_kernel<<<gC, 256, 0, stream>>>(ab, Wo, bo, out);
}